// Round 10
// baseline (99.357 us; speedup 1.0000x reference)
//
#include <hip/hip_runtime.h>
#include <hip/hip_bf16.h>

#define HID 1024
#define HEADS 16
#define FEAT 16
#define HD 64
#define T_LEN 1024
#define NFEAT 136   // 16 diag + 120 off-diag
#define CL 32       // chunk length
#define NC 32       // chunks per head
#define SSTATE (NFEAT * HD)  // 8704

typedef __attribute__((ext_vector_type(8))) short short8;
typedef __attribute__((ext_vector_type(4))) float f32x4;

// upper-triangle index pair tables (i<j of 16)
__device__ const unsigned char IU_d[120] = {
    0,0,0,0,0,0,0,0,0,0,0,0,0,0,0,
    1,1,1,1,1,1,1,1,1,1,1,1,1,1,
    2,2,2,2,2,2,2,2,2,2,2,2,2,
    3,3,3,3,3,3,3,3,3,3,3,3,
    4,4,4,4,4,4,4,4,4,4,4,
    5,5,5,5,5,5,5,5,5,5,
    6,6,6,6,6,6,6,6,6,
    7,7,7,7,7,7,7,7,
    8,8,8,8,8,8,8,
    9,9,9,9,9,9,
    10,10,10,10,10,
    11,11,11,11,
    12,12,12,
    13,13,
    14};
__device__ const unsigned char JU_d[120] = {
    1,2,3,4,5,6,7,8,9,10,11,12,13,14,15,
    2,3,4,5,6,7,8,9,10,11,12,13,14,15,
    3,4,5,6,7,8,9,10,11,12,13,14,15,
    4,5,6,7,8,9,10,11,12,13,14,15,
    5,6,7,8,9,10,11,12,13,14,15,
    6,7,8,9,10,11,12,13,14,15,
    7,8,9,10,11,12,13,14,15,
    8,9,10,11,12,13,14,15,
    9,10,11,12,13,14,15,
    10,11,12,13,14,15,
    11,12,13,14,15,
    12,13,14,15,
    13,14,15,
    14,15,
    15};

// ---------------------------------------------------------------------------
// f32 <-> bf16 helpers
// ---------------------------------------------------------------------------
__device__ __forceinline__ unsigned short f2bf(float f) {
    union { float f; unsigned int u; } x;
    x.f = f;
    unsigned int u = x.u;
    unsigned int r = u + 0x7fffu + ((u >> 16) & 1u);
    return (unsigned short)(r >> 16);
}
__device__ __forceinline__ float bf2f(unsigned short s) {
    union { unsigned int u; float f; } x;
    x.u = ((unsigned int)s) << 16;
    return x.f;
}

// ---------------------------------------------------------------------------
// Reg-staged, conversion-inline pipelined bf16 MFMA GEMM core.
// 512 threads (8 waves 4x2), 128x128 tile, BK=32, per-wave 32x64 (acc[2][4]).
// A: f32 (A_BF16=0, with a_lo selecting lo-part) or bf16 (A_BF16=1).
// B: f32, b_lo selects lo-part.
// Double-buffered LDS; 2 barriers/iter:
//   [bar; write_stage(buf^1) from regs(t=it+1); load_regs(t=it+2); bar;
//    compute(buf)]
// Hazards: write(buf W)@it vs last read of W at compute()@it-1 -> top barrier.
//          compute(buf)@it vs write(buf)@it-1 -> two barriers between.
// ---------------------------------------------------------------------------
template <int A_BF16>
__device__ __forceinline__ void gemm_cvt512(const void* Av, const float* B,
                                            void* Cv, int lda, int ldb, int ldc,
                                            int bm, int bn, int ntiles,
                                            int a_lo, int b_lo, int out_bf16,
                                            unsigned short (&As)[2][4096],
                                            unsigned short (&Bs)[2][4096]) {
    const int tid = threadIdx.x;   // 0..511
    const int wave = tid >> 6;
    const int lane = tid & 63;
    const int wr = wave >> 1;      // 0..3
    const int wc = wave & 1;       // 0..1
    const int fr = lane & 15;
    const int fq = lane >> 4;
    const int srow = tid >> 2;           // 0..127 (staging row)
    const int scol = (tid & 3) << 3;     // 0,8,16,24 (element offset in K-tile)

    // A/B staging pointers (A/B already offset to tile row 0)
    const float* Af = (const float*)Av;
    const unsigned short* Ab = (const unsigned short*)Av;
    const float* Bp = B + (size_t)srow * ldb + scol;

    f32x4 acc[2][4];
#pragma unroll
    for (int i = 0; i < 2; ++i)
#pragma unroll
        for (int j = 0; j < 4; ++j) acc[i][j] = (f32x4)0.f;

    float4 ra0, ra1, rb0, rb1;
    short8 rab;

    auto load_regs = [&](int tile) {
        const int k0 = tile << 5;
        if (A_BF16) {
            rab = *(const short8*)&Ab[(size_t)srow * lda + scol + k0];
        } else {
            const float* ap = Af + (size_t)srow * lda + scol + k0;
            ra0 = *(const float4*)&ap[0];
            ra1 = *(const float4*)&ap[4];
        }
        rb0 = *(const float4*)&Bp[k0];
        rb1 = *(const float4*)&Bp[k0 + 4];
    };
    auto cvt8 = [&](float4 u, float4 w, int lo) -> short8 {
        float x[8] = {u.x, u.y, u.z, u.w, w.x, w.y, w.z, w.w};
        union { unsigned short s[8]; short8 v; } o;
#pragma unroll
        for (int j = 0; j < 8; ++j) {
            unsigned short hb = f2bf(x[j]);
            o.s[j] = lo ? f2bf(x[j] - bf2f(hb)) : hb;
        }
        return o.v;
    };
    auto write_stage = [&](int buf) {
        if (A_BF16)
            *(short8*)&As[buf][srow * 32 + scol] = rab;
        else
            *(short8*)&As[buf][srow * 32 + scol] = cvt8(ra0, ra1, a_lo);
        *(short8*)&Bs[buf][srow * 32 + scol] = cvt8(rb0, rb1, b_lo);
    };
    auto compute = [&](int buf) {
        short8 a[2], b[4];
#pragma unroll
        for (int i = 0; i < 2; ++i)
            a[i] = *(const short8*)&As[buf][(wr * 32 + i * 16 + fr) * 32 + fq * 8];
#pragma unroll
        for (int j = 0; j < 4; ++j)
            b[j] = *(const short8*)&Bs[buf][(wc * 64 + j * 16 + fr) * 32 + fq * 8];
#pragma unroll
        for (int i = 0; i < 2; ++i)
#pragma unroll
            for (int j = 0; j < 4; ++j)
                acc[i][j] = __builtin_amdgcn_mfma_f32_16x16x32_bf16(a[i], b[j], acc[i][j], 0, 0, 0);
    };

    load_regs(0);
    write_stage(0);
    if (ntiles > 1) load_regs(1);
    for (int it = 0; it < ntiles; ++it) {
        __syncthreads();
        if (it + 1 < ntiles) write_stage((it + 1) & 1);
        if (it + 2 < ntiles) load_regs(it + 2);
        __syncthreads();
        compute(it & 1);
    }

#pragma unroll
    for (int i = 0; i < 2; ++i)
#pragma unroll
        for (int j = 0; j < 4; ++j) {
            int col = bn + wc * 64 + j * 16 + fr;
#pragma unroll
            for (int r = 0; r < 4; ++r) {
                int row = bm + wr * 32 + i * 16 + fq * 4 + r;
                if (out_bf16)
                    ((unsigned short*)Cv)[(size_t)row * ldc + col] = f2bf(acc[i][j][r]);
                else
                    ((float*)Cv)[(size_t)row * ldc + col] = acc[i][j][r];
            }
        }
}

// ---------------------------------------------------------------------------
// QKV GEMM with inline f32->bf16 split conversion. 160 blocks x 512 threads.
//  bx<96 : qk split-K partial seg=bx/32: seg0 hi*hi, seg1 lo*hi, seg2 hi*lo
//          C tile of [1024 x 512] (cols 0..255 q via Wq, 256..511 k via Wk)
//  bx>=96: v = hi(hs) @ hi(Wv)^T -> v_b bf16 [1024 x 1024]
// ---------------------------------------------------------------------------
__global__ __launch_bounds__(512) void gemm_qkv(const float* __restrict__ hs,
                                                const float* __restrict__ Wq,
                                                const float* __restrict__ Wk,
                                                const float* __restrict__ Wv,
                                                float* __restrict__ qk_part,
                                                unsigned short* __restrict__ v_b) {
    __shared__ __align__(16) unsigned short As[2][4096];
    __shared__ __align__(16) unsigned short Bs[2][4096];
    const int bx = blockIdx.x;
    if (bx < 96) {
        int seg = bx >> 5, r = bx & 31;
        int bm = (r >> 2) * 128, bn = (r & 3) * 128;
        const float* B = (bn < 256) ? (Wq + (size_t)bn * HID)
                                    : (Wk + (size_t)(bn - 256) * HID);
        gemm_cvt512<0>(hs + (size_t)bm * HID, B,
                       qk_part + (size_t)seg * (1024 * 512),
                       HID, HID, 512, bm, bn, 32,
                       seg == 1, seg == 2, 0, As, Bs);
    } else {
        int r = bx - 96;
        int bm = (r >> 3) * 128, bn = (r & 7) * 128;
        gemm_cvt512<0>(hs + (size_t)bm * HID, Wv + (size_t)bn * HID,
                       v_b, HID, HID, 1024, bm, bn, 32, 0, 0, 1, As, Bs);
    }
}

// ---------------------------------------------------------------------------
// Wo GEMM: A = y_b (bf16), B = Wo (f32, hi) -> out f32. 64 blocks x 512 thr.
// ---------------------------------------------------------------------------
__global__ __launch_bounds__(512) void gemm_wo(const unsigned short* __restrict__ y_b,
                                               const float* __restrict__ Wo,
                                               float* __restrict__ out) {
    __shared__ __align__(16) unsigned short As[2][4096];
    __shared__ __align__(16) unsigned short Bs[2][4096];
    const int r = blockIdx.x;
    const int bm = (r >> 3) * 128, bn = (r & 7) * 128;
    gemm_cvt512<1>(y_b + (size_t)bm * HID, Wo + (size_t)bn * HID,
                   out, HID, HID, 1024, bm, bn, 32, 0, 0, 0, As, Bs);
}

// ---------------------------------------------------------------------------
// LN of one row of q/k (summing 3 split-K partials) -> xn row in LDS.
// ---------------------------------------------------------------------------
__device__ __forceinline__ void ln_row_to_lds(const float* __restrict__ qk_part,
                                              int col0, int h, int t,
                                              const float* __restrict__ gamma,
                                              const float* __restrict__ beta,
                                              float* __restrict__ xn_row) {
    const float* base = qk_part + (size_t)t * 512 + col0 + h * FEAT;
    float x[16];
    float mu = 0.f;
#pragma unroll
    for (int f = 0; f < 16; ++f) {
        x[f] = base[f] + base[f + 524288] + base[f + 1048576];
        mu += x[f];
    }
    mu *= (1.f / 16.f);
    float var = 0.f;
#pragma unroll
    for (int f = 0; f < 16; ++f) {
        float d = x[f] - mu;
        var += d * d;
    }
    var *= (1.f / 16.f);
    float rstd = rsqrtf(var + 1e-5f);
#pragma unroll
    for (int f = 0; f < 16; ++f)
        xn_row[f] = (x[f] - mu) * rstd * gamma[f] + beta[f];
}

// ---------------------------------------------------------------------------
// Phase 1: per-chunk KV sums + Z sums, feature map fused (round-8 verbatim).
// ---------------------------------------------------------------------------
__global__ __launch_bounds__(256) void chunk_kv(const float* __restrict__ qk_part,
                                                const unsigned short* __restrict__ v_b,
                                                const float* __restrict__ gamma,
                                                const float* __restrict__ beta,
                                                float* __restrict__ KV,
                                                float* __restrict__ Z) {
    const int c = blockIdx.x;
    const int h = blockIdx.y;
    const int tid = threadIdx.x;
    __shared__ float xn_s[CL][17];
    __shared__ float pk_s[CL * NFEAT];
    __shared__ unsigned char iu_s[120], ju_s[120];

    const int d = tid & 63;
    const int fg = tid >> 6;

    if (tid < 120) { iu_s[tid] = IU_d[tid]; ju_s[tid] = JU_d[tid]; }

    float v[CL];
#pragma unroll
    for (int t = 0; t < CL; ++t)
        v[t] = bf2f(v_b[(size_t)(c * CL + t) * 1024 + h * HD + d]);

    if (tid < CL)
        ln_row_to_lds(qk_part, 256, h, c * CL + tid, gamma, beta, xn_s[tid]);
    __syncthreads();

    {
        int r = tid >> 3, p = tid & 7;
        const float c1 = 0.25f;
        const float c2 = 0.35355339059327373f;
#pragma unroll
        for (int n = 0; n < 17; ++n) {
            int idx = p * 17 + n;
            float val;
            if (idx < 16) {
                float a = xn_s[r][idx];
                val = a * a * c1;
            } else {
                val = xn_s[r][iu_s[idx - 16]] * xn_s[r][ju_s[idx - 16]] * c2;
            }
            pk_s[r * NFEAT + idx] = val;
        }
    }
    __syncthreads();

    float* kv_out = KV + ((size_t)(h * NC + c)) * SSTATE;
    float* z_out = Z + ((size_t)(h * NC + c)) * NFEAT;
#pragma unroll
    for (int np = 0; np < 17; ++np) {
        int f = fg * 34 + 2 * np;
        float acc0 = 0.f, acc1 = 0.f, z0 = 0.f, z1 = 0.f;
#pragma unroll
        for (int t = 0; t < CL; ++t) {
            float2 pk = *(const float2*)&pk_s[t * NFEAT + f];
            acc0 += pk.x * v[t];
            acc1 += pk.y * v[t];
            z0 += pk.x;
            z1 += pk.y;
        }
        kv_out[(f + 0) * HD + d] = acc0;
        kv_out[(f + 1) * HD + d] = acc1;
        if (d == 0) { z_out[f] = z0; z_out[f + 1] = z1; }
    }
}

// ---------------------------------------------------------------------------
// Phase 2: exclusive prefix scan over chunks (round-8 verbatim).
// ---------------------------------------------------------------------------
__global__ __launch_bounds__(256) void chunk_scan(float* __restrict__ KV,
                                                  float* __restrict__ Z) {
    const int bx = blockIdx.x;
    const int h = blockIdx.y;
    const int tid = threadIdx.x;
    if (bx < 34) {
        float* base = KV + (size_t)h * NC * SSTATE + bx * 256 + tid;
        float val[NC];
#pragma unroll
        for (int c = 0; c < NC; ++c) val[c] = base[(size_t)c * SSTATE];
        float run = 0.f;
#pragma unroll
        for (int c = 0; c < NC; ++c) {
            float t = val[c];
            val[c] = run;
            run += t;
        }
#pragma unroll
        for (int c = 0; c < NC; ++c) base[(size_t)c * SSTATE] = val[c];
    } else if (tid < NFEAT) {
        float* base = Z + (size_t)h * NC * NFEAT + tid;
        float val[NC];
#pragma unroll
        for (int c = 0; c < NC; ++c) val[c] = base[(size_t)c * NFEAT];
        float run = 0.f;
#pragma unroll
        for (int c = 0; c < NC; ++c) {
            float t = val[c];
            val[c] = run;
            run += t;
        }
#pragma unroll
        for (int c = 0; c < NC; ++c) base[(size_t)c * NFEAT] = val[c];
    }
}

// ---------------------------------------------------------------------------
// Phase 3: per-chunk output (round-8 verbatim).
// ---------------------------------------------------------------------------
__global__ __launch_bounds__(256) void chunk_out(const float* __restrict__ qk_part,
                                                 const unsigned short* __restrict__ v_b,
                                                 const float* __restrict__ gamma,
                                                 const float* __restrict__ beta,
                                                 const float* __restrict__ KV,
                                                 const float* __restrict__ Z,
                                                 unsigned short* __restrict__ y_b) {
    const int c = blockIdx.x;
    const int h = blockIdx.y;
    const int tid = threadIdx.x;

    __shared__ float xnq_s[CL][17];
    __shared__ float xnk_s[CL][17];
    __shared__ float pq_s[CL * 137];
    __shared__ float pk_s[CL * 137];
    __shared__ float A_s[CL * CL];
    __shared__ unsigned char iu_s[120], ju_s[120];

    const int d = tid & 63;
    const int tg = tid >> 6;

    if (tid < 120) { iu_s[tid] = IU_d[tid]; ju_s[tid] = JU_d[tid]; }

    float v[CL];
#pragma unroll
    for (int t = 0; t < CL; ++t)
        v[t] = bf2f(v_b[(size_t)(c * CL + t) * 1024 + h * HD + d]);

    if (tid < 64) {
        int mat = tid >> 5;
        int r = tid & 31;
        ln_row_to_lds(qk_part, mat ? 256 : 0, h, c * CL + r, gamma, beta,
                      mat ? xnk_s[r] : xnq_s[r]);
    }
    for (int e = tid; e < CL * CL; e += 256) A_s[e] = 0.f;
    __syncthreads();

    {
        int mat = tid >> 7;
        int r = (tid & 127) >> 2;
        int p = tid & 3;
        const float (*xn)[17] = mat ? xnk_s : xnq_s;
        float* dst = (mat ? pk_s : pq_s) + (size_t)r * 137;
        const float c1 = 0.25f;
        const float c2 = 0.35355339059327373f;
#pragma unroll
        for (int n = 0; n < 34; ++n) {
            int idx = p * 34 + n;
            float val;
            if (idx < 16) {
                float a = xn[r][idx];
                val = a * a * c1;
            } else {
                val = xn[r][iu_s[idx - 16]] * xn[r][ju_s[idx - 16]] * c2;
            }
            dst[idx] = val;
        }
    }
    __syncthreads();

    for (int e = tid; e < 528; e += 256) {
        int t = (int)((sqrtf(8.f * e + 1.f) - 1.f) * 0.5f);
        int s = e - ((t * (t + 1)) >> 1);
        float acc = 0.f;
#pragma unroll 8
        for (int f = 0; f < NFEAT; ++f)
            acc += pq_s[t * 137 + f] * pk_s[s * 137 + f];
        A_s[t * CL + s] = acc;
    }
    __syncthreads();

    const float* kv_pref = KV + ((size_t)(h * NC + c)) * SSTATE;
    const float* z_pref = Z + ((size_t)(h * NC + c)) * NFEAT;

    float num[8], den[8];
#pragma unroll
    for (int i = 0; i < 8; ++i) { num[i] = 0.f; den[i] = 0.f; }

#pragma unroll 8
    for (int f = 0; f < NFEAT; ++f) {
        float sp = kv_pref[f * HD + d];
        float zp = z_pref[f];
#pragma unroll
        for (int i = 0; i < 8; ++i) {
            float pq = pq_s[(tg * 8 + i) * 137 + f];
            num[i] += pq * sp;
            den[i] += pq * zp;
        }
    }
#pragma unroll
    for (int s = 0; s < CL; ++s) {
        float vv = v[s];
#pragma unroll
        for (int i = 0; i < 8; ++i) {
            float a = A_s[(tg * 8 + i) * CL + s];
            num[i] += a * vv;
            den[i] += a;
        }
    }
#pragma unroll
    for (int i = 0; i < 8; ++i) {
        int t = c * CL + tg * 8 + i;
        y_b[(size_t)t * 1024 + h * HD + d] = f2bf(num[i] / (den[i] + 1e-5f));
    }
}

extern "C" void kernel_launch(void* const* d_in, const int* in_sizes, int n_in,
                              void* d_out, int out_size, void* d_ws, size_t ws_size,
                              hipStream_t stream) {
    const float* hs    = (const float*)d_in[0];
    const float* Wq    = (const float*)d_in[1];
    const float* Wk    = (const float*)d_in[2];
    const float* Wv    = (const float*)d_in[3];
    const float* Wo    = (const float*)d_in[4];
    const float* gamma = (const float*)d_in[5];
    const float* beta  = (const float*)d_in[6];
    float* out = (float*)d_out;

    float* ws = (float*)d_ws;
    float* qk_part = ws;                                  // 3*1024*512
    float* KV      = qk_part + 3 * 1024 * 512;            // 16*32*8704
    float* Z       = KV + (size_t)HEADS * NC * SSTATE;    // 16*32*136
    unsigned short* v_b = (unsigned short*)(Z + HEADS * NC * NFEAT);  // 1024*1024
    unsigned short* y_b = v_b + (size_t)1024 * 1024;      // 1024*1024

    gemm_qkv<<<160, dim3(512), 0, stream>>>(hs, Wq, Wk, Wv, qk_part, v_b);

    chunk_kv<<<dim3(NC, HEADS), dim3(256), 0, stream>>>(qk_part, v_b, gamma, beta, KV, Z);
    chunk_scan<<<dim3(35, HEADS), dim3(256), 0, stream>>>(KV, Z);
    chunk_out<<<dim3(NC, HEADS), dim3(256), 0, stream>>>(qk_part, v_b, gamma, beta, KV, Z, y_b);

    gemm_wo<<<64, dim3(512), 0, stream>>>(y_b, Wo, out);
}